// Round 4
// baseline (307.101 us; speedup 1.0000x reference)
//
#include <hip/hip_runtime.h>
#include <hip/hip_bf16.h>

// Fused causal self-attention (GQA) for MI355X/gfx950.
// Shapes: B=2, T=2048, C=1024, H=16, Hkv=4, D=64.
// Round 4: root cause of r1-r3 failures was Kbuf/Vbuf overlap (allocated K/V
// activation buffers at weight size 0.5MB instead of 2MB -> V overwrote K rows
// 1024+). Fixed map; Q/K/V now staged inside d_out (dead until final GEMM).

typedef __attribute__((ext_vector_type(8))) short s16x8;   // 8 x bf16 raw
typedef __attribute__((ext_vector_type(4))) float f32x4;
typedef __attribute__((ext_vector_type(4))) unsigned short u16x4;

#define LOG2E 1.44269504088896340736f

__device__ __forceinline__ float bf2f(unsigned short u) {
  unsigned int i = ((unsigned int)u) << 16;
  return __builtin_bit_cast(float, i);
}
__device__ __forceinline__ unsigned short f2bf(float f) {
  unsigned int i = __builtin_bit_cast(unsigned int, f);
  i += 0x7fffu + ((i >> 16) & 1u);   // RNE
  return (unsigned short)(i >> 16);
}

__device__ __forceinline__ void async16(const void* g, void* l) {
  __builtin_amdgcn_global_load_lds(
      (const __attribute__((address_space(1))) void*)g,
      (__attribute__((address_space(3))) void*)l, 16, 0, 0);
}

// ---------------- prep kernels ----------------

__global__ void conv_f32_to_bf16(const float* __restrict__ in,
                                 unsigned short* __restrict__ out, int n) {
  int i = (blockIdx.x * blockDim.x + threadIdx.x) * 4;
  if (i + 3 < n) {
    float4 v = *(const float4*)(in + i);
    u16x4 o = { f2bf(v.x), f2bf(v.y), f2bf(v.z), f2bf(v.w) };
    *(u16x4*)(out + i) = o;
  }
}

// W [K][N] fp32 -> Wt [N][K] bf16
__global__ void transpose_conv(const float* __restrict__ W,
                               unsigned short* __restrict__ Wt, int K, int N) {
  __shared__ float tile[32][33];
  int n0 = blockIdx.x * 32, k0 = blockIdx.y * 32;
  int tx = threadIdx.x, ty = threadIdx.y;
  for (int i = ty; i < 32; i += 8)
    tile[i][tx] = W[(size_t)(k0 + i) * N + n0 + tx];
  __syncthreads();
  for (int i = ty; i < 32; i += 8)
    Wt[(size_t)(n0 + i) * K + k0 + tx] = f2bf(tile[tx][i]);
}

// In-place RoPE on [rows][nheads*64] bf16; t = row % 2048; optional scale fold.
__global__ void rope_scale(unsigned short* __restrict__ X,
                           const float* __restrict__ cosb,
                           const float* __restrict__ sinb,
                           int nheads, float mul) {
  int idx = blockIdx.x * blockDim.x + threadIdx.x;
  int d = idx & 31;
  int h = (idx >> 5) % nheads;
  int row = idx / (32 * nheads);
  int t = row & 2047;
  size_t base = (size_t)row * (nheads * 64) + h * 64 + d;
  float x1 = bf2f(X[base]), x2 = bf2f(X[base + 32]);
  float c = cosb[t * 32 + d], s = sinb[t * 32 + d];
  X[base]      = f2bf((x1 * c + x2 * s) * mul);
  X[base + 32] = f2bf((-x1 * s + x2 * c) * mul);
}

// ---------------- GEMM: C[M,N] = A[M,K] * Bt[N,K]^T ----------------
// 128x128 tile, BK=32, 4 waves (2x2), each wave 64x64 via 4x4 16x16x32 MFMA.
__global__ __launch_bounds__(256) void gemm_bt(
    const unsigned short* __restrict__ A, const unsigned short* __restrict__ Bt,
    void* __restrict__ Cp, int M, int N, int K, int c_f32) {
  __shared__ unsigned short As[128 * 32];
  __shared__ unsigned short Bs[128 * 32];
  int tid = threadIdx.x;
  int w = tid >> 6, l = tid & 63, g = l >> 4, lr = l & 15;
  int wr = w >> 1, wc = w & 1;
  int m0 = blockIdx.y * 128, n0 = blockIdx.x * 128;

  f32x4 acc[4][4] = {};

  for (int k0 = 0; k0 < K; k0 += 32) {
#pragma unroll
    for (int i = 0; i < 2; ++i) {
      int c = i * 256 + tid;
      int row = c >> 2, cc = (c & 3) * 8;   // lane-linear LDS dest (required)
      async16(A + (size_t)(m0 + row) * K + k0 + cc, (char*)As + c * 16);
      async16(Bt + (size_t)(n0 + row) * K + k0 + cc, (char*)Bs + c * 16);
    }
    __syncthreads();   // compiler drains vmcnt before barrier -> tiles ready

    s16x8 af[4], bfr[4];
#pragma unroll
    for (int m = 0; m < 4; ++m)
      af[m] = *(const s16x8*)(As + (wr * 64 + m * 16 + lr) * 32 + g * 8);
#pragma unroll
    for (int n = 0; n < 4; ++n)
      bfr[n] = *(const s16x8*)(Bs + (wc * 64 + n * 16 + lr) * 32 + g * 8);
#pragma unroll
    for (int m = 0; m < 4; ++m)
#pragma unroll
      for (int n = 0; n < 4; ++n)
        acc[m][n] = __builtin_amdgcn_mfma_f32_16x16x32_bf16(af[m], bfr[n],
                                                            acc[m][n], 0, 0, 0);
    __syncthreads();
  }

  // C/D layout: row = (l>>4)*4 + r, col = l&15  [HW-verified]
  if (c_f32) {
    float* C = (float*)Cp;
#pragma unroll
    for (int m = 0; m < 4; ++m)
#pragma unroll
      for (int n = 0; n < 4; ++n)
#pragma unroll
        for (int r = 0; r < 4; ++r)
          C[(size_t)(m0 + wr * 64 + m * 16 + g * 4 + r) * N +
            n0 + wc * 64 + n * 16 + lr] = acc[m][n][r];
  } else {
    unsigned short* C = (unsigned short*)Cp;
#pragma unroll
    for (int m = 0; m < 4; ++m)
#pragma unroll
      for (int n = 0; n < 4; ++n)
#pragma unroll
        for (int r = 0; r < 4; ++r)
          C[(size_t)(m0 + wr * 64 + m * 16 + g * 4 + r) * N +
            n0 + wc * 64 + n * 16 + lr] = f2bf(acc[m][n][r]);
  }
}

// ---------------- flash attention ----------------
// grid (T/64, B*H); block 256 = 4 waves; wave w owns q rows [q0+16w, q0+16w+16).
// KV tiles of 64. Q pre-scaled by 1/sqrt(D).
__global__ __launch_bounds__(256) void attn_fused(
    const unsigned short* __restrict__ Q, const unsigned short* __restrict__ Kb,
    const unsigned short* __restrict__ Vb, unsigned short* __restrict__ Y) {
  __shared__ unsigned short Kt[64 * 64];      // [kv][d]
  __shared__ unsigned short Vt[64 * 64];      // [d][kv] (transposed)
  __shared__ unsigned short Pb[4][16 * 64];   // per-wave P buffer

  const int T = 2048;
  int tid = threadIdx.x;
  int w = tid >> 6, l = tid & 63, g = l >> 4, lr = l & 15;
  int bh = blockIdx.y, b = bh >> 4, h = bh & 15, kvh = h >> 2;
  int q0 = blockIdx.x * 64, qw = q0 + w * 16;

  const unsigned short* Qp = Q + (size_t)b * T * 1024 + h * 64;
  const unsigned short* Kp = Kb + (size_t)b * T * 256 + kvh * 64;
  const unsigned short* Vp = Vb + (size_t)b * T * 256 + kvh * 64;

  s16x8 qf[2];
#pragma unroll
  for (int ks = 0; ks < 2; ++ks)
    qf[ks] = *(const s16x8*)(Qp + (size_t)(qw + lr) * 1024 + ks * 32 + g * 8);

  f32x4 o[4] = {};
  float mrun[4], lrun[4];
#pragma unroll
  for (int r = 0; r < 4; ++r) { mrun[r] = -1e30f; lrun[r] = 0.f; }

  unsigned short* Pw = Pb[w];
  int ntiles = blockIdx.x + 1;   // causal: kv0 <= q0

  for (int it = 0; it < ntiles; ++it) {
    int kv0 = it * 64;
    // stage K tile [kv][d] via global_load_lds (lane-linear dest)
#pragma unroll
    for (int i = 0; i < 2; ++i) {
      int c = i * 256 + tid;
      int row = c >> 3, off = (c & 7) * 8;
      async16(Kp + (size_t)(kv0 + row) * 256 + off, (char*)Kt + c * 16);
    }
    // stage V transposed [d][kv] (reg round-trip)
#pragma unroll
    for (int i = 0; i < 2; ++i) {
      int c = i * 256 + tid;
      int kv = c & 63, d0 = (c >> 6) * 8;
      s16x8 vv = *(const s16x8*)(Vp + (size_t)(kv0 + kv) * 256 + d0);
#pragma unroll
      for (int j = 0; j < 8; ++j)
        Vt[(d0 + j) * 64 + kv] = (unsigned short)vv[j];
    }
    __syncthreads();

    // S = Q K^T : C/D rows = q (g*4+r), cols = kv (nf*16+lr)
    f32x4 s[4] = {};
#pragma unroll
    for (int nf = 0; nf < 4; ++nf)
#pragma unroll
      for (int ks = 0; ks < 2; ++ks) {
        s16x8 kf = *(const s16x8*)(Kt + (nf * 16 + lr) * 64 + ks * 32 + g * 8);
        s[nf] = __builtin_amdgcn_mfma_f32_16x16x32_bf16(qf[ks], kf, s[nf], 0, 0, 0);
      }

    if (kv0 == q0) {   // diagonal tile: causal mask
#pragma unroll
      for (int nf = 0; nf < 4; ++nf) {
        int kvg = kv0 + nf * 16 + lr;
#pragma unroll
        for (int r = 0; r < 4; ++r)
          if (kvg > qw + g * 4 + r) s[nf][r] = -1e30f;
      }
    }

    // online softmax per row r (row lives across the 16 lanes of group g)
#pragma unroll
    for (int r = 0; r < 4; ++r) {
      float mt = fmaxf(fmaxf(s[0][r], s[1][r]), fmaxf(s[2][r], s[3][r]));
#pragma unroll
      for (int msk = 1; msk <= 8; msk <<= 1) mt = fmaxf(mt, __shfl_xor(mt, msk, 64));
      float mnew = fmaxf(mrun[r], mt);
      float corr = exp2f((mrun[r] - mnew) * LOG2E);
      float psum = 0.f;
#pragma unroll
      for (int nf = 0; nf < 4; ++nf) {
        float p = exp2f((s[nf][r] - mnew) * LOG2E);
        s[nf][r] = p;
        psum += p;
      }
#pragma unroll
      for (int msk = 1; msk <= 8; msk <<= 1) psum += __shfl_xor(psum, msk, 64);
      lrun[r] = lrun[r] * corr + psum;
      mrun[r] = mnew;
#pragma unroll
      for (int d0 = 0; d0 < 4; ++d0) o[d0][r] *= corr;
    }

    // P -> per-wave LDS (C/D layout), then re-read as A-fragments.
#pragma unroll
    for (int nf = 0; nf < 4; ++nf)
#pragma unroll
      for (int r = 0; r < 4; ++r)
        Pw[(g * 4 + r) * 64 + nf * 16 + lr] = f2bf(s[nf][r]);
    asm volatile("s_waitcnt lgkmcnt(0)" ::: "memory");
    __builtin_amdgcn_sched_barrier(0);   // rule #18: keep MFMA below the wait

    s16x8 pf[2];
#pragma unroll
    for (int ks = 0; ks < 2; ++ks)
      pf[ks] = *(const s16x8*)(Pw + lr * 64 + ks * 32 + g * 8);
#pragma unroll
    for (int d0 = 0; d0 < 4; ++d0)
#pragma unroll
      for (int ks = 0; ks < 2; ++ks) {
        s16x8 vf = *(const s16x8*)(Vt + (d0 * 16 + lr) * 64 + ks * 32 + g * 8);
        o[d0] = __builtin_amdgcn_mfma_f32_16x16x32_bf16(pf[ks], vf, o[d0], 0, 0, 0);
      }
    __syncthreads();
  }

#pragma unroll
  for (int r = 0; r < 4; ++r) {
    float inv = 1.f / lrun[r];
    size_t rowoff = (size_t)(b * T + qw + g * 4 + r) * 1024 + h * 64;
#pragma unroll
    for (int d0 = 0; d0 < 4; ++d0)
      Y[rowoff + d0 * 16 + lr] = f2bf(o[d0][r] * inv);
  }
}

// ---------------- launch ----------------

extern "C" void kernel_launch(void* const* d_in, const int* in_sizes, int n_in,
                              void* d_out, int out_size, void* d_ws, size_t ws_size,
                              hipStream_t stream) {
  const float* x    = (const float*)d_in[0];
  const float* cosb = (const float*)d_in[1];
  const float* sinb = (const float*)d_in[2];
  const float* Wq   = (const float*)d_in[3];
  const float* Wk   = (const float*)d_in[4];
  const float* Wv   = (const float*)d_in[5];
  const float* Wo   = (const float*)d_in[6];
  float* out = (float*)d_out;

  // Buffer map (sizes in bytes):
  //   d_out (16 MB): Qb 0..8M | Kbuf 8M..10M | Vbuf 10M..12M   (dead at final gemm)
  //   d_ws:          xb 0..8M | Wqt 8..10M | Wkt 10..10.5M | Wvt 10.5..11M | Wot 11..13M
  char* ob = (char*)d_out;
  char* ws = (char*)d_ws;
  const size_t MB = 1024 * 1024;
  unsigned short* Qb   = (unsigned short*)(ob);
  unsigned short* Kbuf = (unsigned short*)(ob + 8 * MB);
  unsigned short* Vbuf = (unsigned short*)(ob + 10 * MB);
  unsigned short* xb   = (unsigned short*)(ws);
  unsigned short* Wqt  = (unsigned short*)(ws + 8 * MB);
  unsigned short* Wkt  = (unsigned short*)(ws + 10 * MB);
  unsigned short* Wvt  = (unsigned short*)(ws + 10 * MB + 512 * 1024);
  unsigned short* Wot  = (unsigned short*)(ws + 11 * MB);
  unsigned short* Yb   = xb;   // alias: x-content dead after QKV gemms

  // prep
  conv_f32_to_bf16<<<4096, 256, 0, stream>>>(x, xb, 4096 * 1024);
  transpose_conv<<<dim3(32, 32), dim3(32, 8), 0, stream>>>(Wq, Wqt, 1024, 1024);
  transpose_conv<<<dim3(8, 32), dim3(32, 8), 0, stream>>>(Wk, Wkt, 1024, 256);
  transpose_conv<<<dim3(8, 32), dim3(32, 8), 0, stream>>>(Wv, Wvt, 1024, 256);
  transpose_conv<<<dim3(32, 32), dim3(32, 8), 0, stream>>>(Wo, Wot, 1024, 1024);

  // projections (bf16 out)
  gemm_bt<<<dim3(8, 32), 256, 0, stream>>>(xb, Wqt, Qb, 4096, 1024, 1024, 0);
  gemm_bt<<<dim3(2, 32), 256, 0, stream>>>(xb, Wkt, Kbuf, 4096, 256, 1024, 0);
  gemm_bt<<<dim3(2, 32), 256, 0, stream>>>(xb, Wvt, Vbuf, 4096, 256, 1024, 0);

  // RoPE; fold 1/sqrt(64)=0.125 into Q (exact pow2)
  rope_scale<<<(4096 * 16 * 32) / 256, 256, 0, stream>>>(Qb, cosb, sinb, 16, 0.125f);
  rope_scale<<<(4096 * 4 * 32) / 256, 256, 0, stream>>>(Kbuf, cosb, sinb, 4, 1.0f);

  // attention -> Yb bf16 [B*T][1024]
  attn_fused<<<dim3(32, 32), 256, 0, stream>>>(Qb, Kbuf, Vbuf, Yb);

  // output projection (fp32 out, overwrites all of d_out)
  gemm_bt<<<dim3(8, 32), 256, 0, stream>>>(Yb, Wot, out, 4096, 1024, 1024, 1);
}

// Round 5
// 208.485 us; speedup vs baseline: 1.4730x; 1.4730x over previous
//
#include <hip/hip_runtime.h>
#include <hip/hip_bf16.h>

// Fused causal self-attention (GQA) for MI355X/gfx950.
// Shapes: B=2, T=2048, C=1024, H=16, Hkv=4, D=64.
// Round 5: attack attn_fused (188/307 us, 16-way LDS bank conflicts, tail
// imbalance): T2 XOR-swizzle on Kt/Vt/P, heavy-first block order, setprio.

typedef __attribute__((ext_vector_type(8))) short s16x8;   // 8 x bf16 raw
typedef __attribute__((ext_vector_type(4))) float f32x4;
typedef __attribute__((ext_vector_type(4))) unsigned short u16x4;

#define LOG2E 1.44269504088896340736f

__device__ __forceinline__ float bf2f(unsigned short u) {
  unsigned int i = ((unsigned int)u) << 16;
  return __builtin_bit_cast(float, i);
}
__device__ __forceinline__ unsigned short f2bf(float f) {
  unsigned int i = __builtin_bit_cast(unsigned int, f);
  i += 0x7fffu + ((i >> 16) & 1u);   // RNE
  return (unsigned short)(i >> 16);
}

__device__ __forceinline__ void async16(const void* g, void* l) {
  __builtin_amdgcn_global_load_lds(
      (const __attribute__((address_space(1))) void*)g,
      (__attribute__((address_space(3))) void*)l, 16, 0, 0);
}

// ---------------- prep kernels ----------------

__global__ void conv_f32_to_bf16(const float* __restrict__ in,
                                 unsigned short* __restrict__ out, int n) {
  int i = (blockIdx.x * blockDim.x + threadIdx.x) * 4;
  if (i + 3 < n) {
    float4 v = *(const float4*)(in + i);
    u16x4 o = { f2bf(v.x), f2bf(v.y), f2bf(v.z), f2bf(v.w) };
    *(u16x4*)(out + i) = o;
  }
}

// W [K][N] fp32 -> Wt [N][K] bf16
__global__ void transpose_conv(const float* __restrict__ W,
                               unsigned short* __restrict__ Wt, int K, int N) {
  __shared__ float tile[32][33];
  int n0 = blockIdx.x * 32, k0 = blockIdx.y * 32;
  int tx = threadIdx.x, ty = threadIdx.y;
  for (int i = ty; i < 32; i += 8)
    tile[i][tx] = W[(size_t)(k0 + i) * N + n0 + tx];
  __syncthreads();
  for (int i = ty; i < 32; i += 8)
    Wt[(size_t)(n0 + i) * K + k0 + tx] = f2bf(tile[tx][i]);
}

// In-place RoPE on [rows][nheads*64] bf16; t = row % 2048; optional scale fold.
__global__ void rope_scale(unsigned short* __restrict__ X,
                           const float* __restrict__ cosb,
                           const float* __restrict__ sinb,
                           int nheads, float mul) {
  int idx = blockIdx.x * blockDim.x + threadIdx.x;
  int d = idx & 31;
  int h = (idx >> 5) % nheads;
  int row = idx / (32 * nheads);
  int t = row & 2047;
  size_t base = (size_t)row * (nheads * 64) + h * 64 + d;
  float x1 = bf2f(X[base]), x2 = bf2f(X[base + 32]);
  float c = cosb[t * 32 + d], s = sinb[t * 32 + d];
  X[base]      = f2bf((x1 * c + x2 * s) * mul);
  X[base + 32] = f2bf((-x1 * s + x2 * c) * mul);
}

// ---------------- GEMM: C[M,N] = A[M,K] * Bt[N,K]^T ----------------
// 128x128 tile, BK=32, 4 waves (2x2), each wave 64x64 via 4x4 16x16x32 MFMA.
__global__ __launch_bounds__(256) void gemm_bt(
    const unsigned short* __restrict__ A, const unsigned short* __restrict__ Bt,
    void* __restrict__ Cp, int M, int N, int K, int c_f32) {
  __shared__ unsigned short As[128 * 32];
  __shared__ unsigned short Bs[128 * 32];
  int tid = threadIdx.x;
  int w = tid >> 6, l = tid & 63, g = l >> 4, lr = l & 15;
  int wr = w >> 1, wc = w & 1;
  int m0 = blockIdx.y * 128, n0 = blockIdx.x * 128;

  f32x4 acc[4][4] = {};

  for (int k0 = 0; k0 < K; k0 += 32) {
#pragma unroll
    for (int i = 0; i < 2; ++i) {
      int c = i * 256 + tid;
      int row = c >> 2, cc = (c & 3) * 8;   // lane-linear LDS dest (required)
      async16(A + (size_t)(m0 + row) * K + k0 + cc, (char*)As + c * 16);
      async16(Bt + (size_t)(n0 + row) * K + k0 + cc, (char*)Bs + c * 16);
    }
    __syncthreads();

    s16x8 af[4], bfr[4];
#pragma unroll
    for (int m = 0; m < 4; ++m)
      af[m] = *(const s16x8*)(As + (wr * 64 + m * 16 + lr) * 32 + g * 8);
#pragma unroll
    for (int n = 0; n < 4; ++n)
      bfr[n] = *(const s16x8*)(Bs + (wc * 64 + n * 16 + lr) * 32 + g * 8);
#pragma unroll
    for (int m = 0; m < 4; ++m)
#pragma unroll
      for (int n = 0; n < 4; ++n)
        acc[m][n] = __builtin_amdgcn_mfma_f32_16x16x32_bf16(af[m], bfr[n],
                                                            acc[m][n], 0, 0, 0);
    __syncthreads();
  }

  // C/D layout: row = (l>>4)*4 + r, col = l&15  [HW-verified]
  if (c_f32) {
    float* C = (float*)Cp;
#pragma unroll
    for (int m = 0; m < 4; ++m)
#pragma unroll
      for (int n = 0; n < 4; ++n)
#pragma unroll
        for (int r = 0; r < 4; ++r)
          C[(size_t)(m0 + wr * 64 + m * 16 + g * 4 + r) * N +
            n0 + wc * 64 + n * 16 + lr] = acc[m][n][r];
  } else {
    unsigned short* C = (unsigned short*)Cp;
#pragma unroll
    for (int m = 0; m < 4; ++m)
#pragma unroll
      for (int n = 0; n < 4; ++n)
#pragma unroll
        for (int r = 0; r < 4; ++r)
          C[(size_t)(m0 + wr * 64 + m * 16 + g * 4 + r) * N +
            n0 + wc * 64 + n * 16 + lr] = f2bf(acc[m][n][r]);
  }
}

// ---------------- flash attention ----------------
// 1D grid of 1024 blocks, heavy-first: qt = 31-(n>>5), bh = n&31.
// block 256 = 4 waves; wave w owns q rows [q0+16w, q0+16w+16). KV tiles of 64.
// All LDS tiles XOR-swizzled: byte ^= ((row&7)<<4)  (T2; kills 16-way conflicts).
__global__ __launch_bounds__(256) void attn_fused(
    const unsigned short* __restrict__ Q, const unsigned short* __restrict__ Kb,
    const unsigned short* __restrict__ Vb, unsigned short* __restrict__ Y) {
  __shared__ unsigned short Kt[64 * 64];      // [kv][d], swizzled
  __shared__ unsigned short Vt[64 * 64];      // [d][kv], swizzled
  __shared__ unsigned short Pb[4][16 * 64];   // per-wave P, swizzled

  const int T = 2048;
  int tid = threadIdx.x;
  int w = tid >> 6, l = tid & 63, g = l >> 4, lr = l & 15;
  int n = blockIdx.x;
  int qt = 31 - (n >> 5);              // heavy blocks dispatch first
  int bh = n & 31, b = bh >> 4, h = bh & 15, kvh = h >> 2;
  int q0 = qt * 64, qw = q0 + w * 16;
  int sx = lr & 7;                     // read-side swizzle key

  const unsigned short* Qp = Q + (size_t)b * T * 1024 + h * 64;
  const unsigned short* Kp = Kb + (size_t)b * T * 256 + kvh * 64;
  const unsigned short* Vp = Vb + (size_t)b * T * 256 + kvh * 64;

  s16x8 qf[2];
#pragma unroll
  for (int ks = 0; ks < 2; ++ks)
    qf[ks] = *(const s16x8*)(Qp + (size_t)(qw + lr) * 1024 + ks * 32 + g * 8);

  f32x4 o[4] = {};
  float mrun[4], lrun[4];
#pragma unroll
  for (int r = 0; r < 4; ++r) { mrun[r] = -1e30f; lrun[r] = 0.f; }

  unsigned short* Pw = Pb[w];
  int ntiles = qt + 1;   // causal: kv0 <= q0

  for (int it = 0; it < ntiles; ++it) {
    int kv0 = it * 64;
    // stage K tile [kv][d]: linear LDS dest, pre-swizzled global source (m173)
#pragma unroll
    for (int i = 0; i < 2; ++i) {
      int c = i * 256 + tid;
      int row = c >> 3;
      int srcc = ((c & 7) ^ (row & 7)) * 8;
      async16(Kp + (size_t)(kv0 + row) * 256 + srcc, (char*)Kt + c * 16);
    }
    // stage V transposed [d][kv], swizzled write
#pragma unroll
    for (int i = 0; i < 2; ++i) {
      int c = i * 256 + tid;
      int kv = c & 63, d0 = (c >> 6) * 8;
      s16x8 vv = *(const s16x8*)(Vp + (size_t)(kv0 + kv) * 256 + d0);
#pragma unroll
      for (int j = 0; j < 8; ++j)
        Vt[(d0 + j) * 64 + (kv ^ (j * 8))] = (unsigned short)vv[j];
    }
    __syncthreads();

    // S = Q K^T : C/D rows = q (g*4+r), cols = kv (nf*16+lr)
    f32x4 s[4] = {};
    __builtin_amdgcn_s_setprio(1);
#pragma unroll
    for (int nf = 0; nf < 4; ++nf)
#pragma unroll
      for (int ks = 0; ks < 2; ++ks) {
        s16x8 kf = *(const s16x8*)(Kt + (nf * 16 + lr) * 64 +
                                   ((ks * 4 + g) ^ sx) * 8);
        s[nf] = __builtin_amdgcn_mfma_f32_16x16x32_bf16(qf[ks], kf, s[nf], 0, 0, 0);
      }
    __builtin_amdgcn_s_setprio(0);

    if (kv0 == q0) {   // diagonal tile: causal mask
#pragma unroll
      for (int nf = 0; nf < 4; ++nf) {
        int kvg = kv0 + nf * 16 + lr;
#pragma unroll
        for (int r = 0; r < 4; ++r)
          if (kvg > qw + g * 4 + r) s[nf][r] = -1e30f;
      }
    }

    // online softmax per row r (row lives across the 16 lanes of group g)
#pragma unroll
    for (int r = 0; r < 4; ++r) {
      float mt = fmaxf(fmaxf(s[0][r], s[1][r]), fmaxf(s[2][r], s[3][r]));
#pragma unroll
      for (int msk = 1; msk <= 8; msk <<= 1) mt = fmaxf(mt, __shfl_xor(mt, msk, 64));
      float mnew = fmaxf(mrun[r], mt);
      float corr = exp2f((mrun[r] - mnew) * LOG2E);
      float psum = 0.f;
#pragma unroll
      for (int nf = 0; nf < 4; ++nf) {
        float p = exp2f((s[nf][r] - mnew) * LOG2E);
        s[nf][r] = p;
        psum += p;
      }
#pragma unroll
      for (int msk = 1; msk <= 8; msk <<= 1) psum += __shfl_xor(psum, msk, 64);
      lrun[r] = lrun[r] * corr + psum;
      mrun[r] = mnew;
#pragma unroll
      for (int d0 = 0; d0 < 4; ++d0) o[d0][r] *= corr;
    }

    // P -> per-wave LDS (swizzled), then re-read as A-fragments.
#pragma unroll
    for (int nf = 0; nf < 4; ++nf)
#pragma unroll
      for (int r = 0; r < 4; ++r) {
        int prow = g * 4 + r;
        Pw[prow * 64 + ((nf * 16 + lr) ^ ((prow & 7) * 8))] = f2bf(s[nf][r]);
      }
    asm volatile("s_waitcnt lgkmcnt(0)" ::: "memory");
    __builtin_amdgcn_sched_barrier(0);   // rule #18: keep MFMA below the wait

    s16x8 pf[2];
#pragma unroll
    for (int ks = 0; ks < 2; ++ks)
      pf[ks] = *(const s16x8*)(Pw + lr * 64 + ((ks * 4 + g) ^ sx) * 8);
    __builtin_amdgcn_s_setprio(1);
#pragma unroll
    for (int d0 = 0; d0 < 4; ++d0)
#pragma unroll
      for (int ks = 0; ks < 2; ++ks) {
        s16x8 vf = *(const s16x8*)(Vt + (d0 * 16 + lr) * 64 +
                                   ((ks * 4 + g) ^ sx) * 8);
        o[d0] = __builtin_amdgcn_mfma_f32_16x16x32_bf16(pf[ks], vf, o[d0], 0, 0, 0);
      }
    __builtin_amdgcn_s_setprio(0);
    __syncthreads();
  }

#pragma unroll
  for (int r = 0; r < 4; ++r) {
    float inv = 1.f / lrun[r];
    size_t rowoff = (size_t)(b * T + qw + g * 4 + r) * 1024 + h * 64;
#pragma unroll
    for (int d0 = 0; d0 < 4; ++d0)
      Y[rowoff + d0 * 16 + lr] = f2bf(o[d0][r] * inv);
  }
}

// ---------------- launch ----------------

extern "C" void kernel_launch(void* const* d_in, const int* in_sizes, int n_in,
                              void* d_out, int out_size, void* d_ws, size_t ws_size,
                              hipStream_t stream) {
  const float* x    = (const float*)d_in[0];
  const float* cosb = (const float*)d_in[1];
  const float* sinb = (const float*)d_in[2];
  const float* Wq   = (const float*)d_in[3];
  const float* Wk   = (const float*)d_in[4];
  const float* Wv   = (const float*)d_in[5];
  const float* Wo   = (const float*)d_in[6];
  float* out = (float*)d_out;

  // Buffer map:
  //   d_out (16 MB): Qb 0..8M | Kbuf 8..10M | Vbuf 10..12M  (dead at final gemm)
  //   d_ws:          xb 0..8M | Wqt 8..10M | Wkt 10..10.5M | Wvt 10.5..11M | Wot 11..13M
  char* ob = (char*)d_out;
  char* ws = (char*)d_ws;
  const size_t MB = 1024 * 1024;
  unsigned short* Qb   = (unsigned short*)(ob);
  unsigned short* Kbuf = (unsigned short*)(ob + 8 * MB);
  unsigned short* Vbuf = (unsigned short*)(ob + 10 * MB);
  unsigned short* xb   = (unsigned short*)(ws);
  unsigned short* Wqt  = (unsigned short*)(ws + 8 * MB);
  unsigned short* Wkt  = (unsigned short*)(ws + 10 * MB);
  unsigned short* Wvt  = (unsigned short*)(ws + 10 * MB + 512 * 1024);
  unsigned short* Wot  = (unsigned short*)(ws + 11 * MB);
  unsigned short* Yb   = xb;   // alias: x-content dead after QKV gemms

  conv_f32_to_bf16<<<4096, 256, 0, stream>>>(x, xb, 4096 * 1024);
  transpose_conv<<<dim3(32, 32), dim3(32, 8), 0, stream>>>(Wq, Wqt, 1024, 1024);
  transpose_conv<<<dim3(8, 32), dim3(32, 8), 0, stream>>>(Wk, Wkt, 1024, 256);
  transpose_conv<<<dim3(8, 32), dim3(32, 8), 0, stream>>>(Wv, Wvt, 1024, 256);
  transpose_conv<<<dim3(32, 32), dim3(32, 8), 0, stream>>>(Wo, Wot, 1024, 1024);

  gemm_bt<<<dim3(8, 32), 256, 0, stream>>>(xb, Wqt, Qb, 4096, 1024, 1024, 0);
  gemm_bt<<<dim3(2, 32), 256, 0, stream>>>(xb, Wkt, Kbuf, 4096, 256, 1024, 0);
  gemm_bt<<<dim3(2, 32), 256, 0, stream>>>(xb, Wvt, Vbuf, 4096, 256, 1024, 0);

  rope_scale<<<(4096 * 16 * 32) / 256, 256, 0, stream>>>(Qb, cosb, sinb, 16, 0.125f);
  rope_scale<<<(4096 * 4 * 32) / 256, 256, 0, stream>>>(Kbuf, cosb, sinb, 4, 1.0f);

  attn_fused<<<dim3(1024), 256, 0, stream>>>(Qb, Kbuf, Vbuf, Yb);

  gemm_bt<<<dim3(8, 32), 256, 0, stream>>>(Yb, Wot, out, 4096, 1024, 1024, 1);
}

// Round 6
// 165.007 us; speedup vs baseline: 1.8611x; 1.2635x over previous
//
#include <hip/hip_runtime.h>
#include <hip/hip_bf16.h>

// Fused causal self-attention (GQA) for MI355X/gfx950.
// Shapes: B=2, T=2048, C=1024, H=16, Hkv=4, D=64.
// Round 6: fused QKV gemm (packed [4096][1536], 128x64 tiles -> 768 blocks),
// gemm LDS 4-key swizzle, attn KVBLK=128 + defer-max + masked-fragment skip.

typedef __attribute__((ext_vector_type(8))) short s16x8;   // 8 x bf16 raw
typedef __attribute__((ext_vector_type(4))) float f32x4;
typedef __attribute__((ext_vector_type(4))) unsigned short u16x4;

#define LOG2E 1.44269504088896340736f

__device__ __forceinline__ float bf2f(unsigned short u) {
  unsigned int i = ((unsigned int)u) << 16;
  return __builtin_bit_cast(float, i);
}
__device__ __forceinline__ unsigned short f2bf(float f) {
  unsigned int i = __builtin_bit_cast(unsigned int, f);
  i += 0x7fffu + ((i >> 16) & 1u);   // RNE
  return (unsigned short)(i >> 16);
}

__device__ __forceinline__ void async16(const void* g, void* l) {
  __builtin_amdgcn_global_load_lds(
      (const __attribute__((address_space(1))) void*)g,
      (__attribute__((address_space(3))) void*)l, 16, 0, 0);
}

// ---------------- prep kernels ----------------

__global__ void conv_f32_to_bf16(const float* __restrict__ in,
                                 unsigned short* __restrict__ out, int n) {
  int i = (blockIdx.x * blockDim.x + threadIdx.x) * 4;
  if (i + 3 < n) {
    float4 v = *(const float4*)(in + i);
    u16x4 o = { f2bf(v.x), f2bf(v.y), f2bf(v.z), f2bf(v.w) };
    *(u16x4*)(out + i) = o;
  }
}

// W [K][N] fp32 -> Wt [N][K] bf16
__global__ void transpose_conv(const float* __restrict__ W,
                               unsigned short* __restrict__ Wt, int K, int N) {
  __shared__ float tile[32][33];
  int n0 = blockIdx.x * 32, k0 = blockIdx.y * 32;
  int tx = threadIdx.x, ty = threadIdx.y;
  for (int i = ty; i < 32; i += 8)
    tile[i][tx] = W[(size_t)(k0 + i) * N + n0 + tx];
  __syncthreads();
  for (int i = ty; i < 32; i += 8)
    Wt[(size_t)(n0 + i) * K + k0 + tx] = f2bf(tile[tx][i]);
}

// RoPE on packed QKV [4096][1536]: heads 0..15 = Q (scaled 0.125),
// heads 16..19 = K at col offset 1024. t = row % 2048.
__global__ void rope_qk(unsigned short* __restrict__ QKV,
                        const float* __restrict__ cosb,
                        const float* __restrict__ sinb) {
  int idx = blockIdx.x * blockDim.x + threadIdx.x;
  int d = idx & 31;
  int hh = (idx >> 5) % 20;
  int row = idx / (32 * 20);
  int t = row & 2047;
  size_t base;
  float mul;
  if (hh < 16) { base = (size_t)row * 1536 + hh * 64 + d;               mul = 0.125f; }
  else         { base = (size_t)row * 1536 + 1024 + (hh - 16) * 64 + d; mul = 1.0f;   }
  float x1 = bf2f(QKV[base]), x2 = bf2f(QKV[base + 32]);
  float c = cosb[t * 32 + d], s = sinb[t * 32 + d];
  QKV[base]      = f2bf((x1 * c + x2 * s) * mul);
  QKV[base + 32] = f2bf((-x1 * s + x2 * c) * mul);
}

// ---------------- GEMM: C[M,N] = A[M,K] * Bt[N,K]^T ----------------
// 128x64 tile, BK=32, 4 waves (2x2), wave = 64x32 via 4x2 16x16x32 MFMA.
// LDS 4-key XOR swizzle (unit ^= row&3) via pre-swizzled global source;
// A and B swizzle identically -> k-mapping cancels (provably correct).
__global__ __launch_bounds__(256) void gemm_bt(
    const unsigned short* __restrict__ A, const unsigned short* __restrict__ Bt,
    void* __restrict__ Cp, int M, int N, int K, int c_f32) {
  __shared__ unsigned short As[128 * 32];
  __shared__ unsigned short Bs[64 * 32];
  int tid = threadIdx.x;
  int w = tid >> 6, l = tid & 63, g = l >> 4, lr = l & 15;
  int wr = w >> 1, wc = w & 1;
  int m0 = blockIdx.y * 128, n0 = blockIdx.x * 64;
  int sk = lr & 3;   // fragment-read swizzle key

  f32x4 acc[4][2] = {};

  for (int k0 = 0; k0 < K; k0 += 32) {
#pragma unroll
    for (int i = 0; i < 2; ++i) {
      int c = i * 256 + tid;
      int row = c >> 2, srcc = ((c & 3) ^ (row & 3)) * 8;
      async16(A + (size_t)(m0 + row) * K + k0 + srcc, (char*)As + c * 16);
    }
    {
      int c = tid;
      int row = c >> 2, srcc = ((c & 3) ^ (row & 3)) * 8;
      async16(Bt + (size_t)(n0 + row) * K + k0 + srcc, (char*)Bs + c * 16);
    }
    __syncthreads();

    s16x8 af[4], bfr[2];
#pragma unroll
    for (int m = 0; m < 4; ++m)
      af[m] = *(const s16x8*)(As + (wr * 64 + m * 16 + lr) * 32 + (g ^ sk) * 8);
#pragma unroll
    for (int n = 0; n < 2; ++n)
      bfr[n] = *(const s16x8*)(Bs + (wc * 32 + n * 16 + lr) * 32 + (g ^ sk) * 8);
#pragma unroll
    for (int m = 0; m < 4; ++m)
#pragma unroll
      for (int n = 0; n < 2; ++n)
        acc[m][n] = __builtin_amdgcn_mfma_f32_16x16x32_bf16(af[m], bfr[n],
                                                            acc[m][n], 0, 0, 0);
    __syncthreads();
  }

  // C/D layout: row = (l>>4)*4 + r, col = l&15  [HW-verified]
  if (c_f32) {
    float* C = (float*)Cp;
#pragma unroll
    for (int m = 0; m < 4; ++m)
#pragma unroll
      for (int n = 0; n < 2; ++n)
#pragma unroll
        for (int r = 0; r < 4; ++r)
          C[(size_t)(m0 + wr * 64 + m * 16 + g * 4 + r) * N +
            n0 + wc * 32 + n * 16 + lr] = acc[m][n][r];
  } else {
    unsigned short* C = (unsigned short*)Cp;
#pragma unroll
    for (int m = 0; m < 4; ++m)
#pragma unroll
      for (int n = 0; n < 2; ++n)
#pragma unroll
        for (int r = 0; r < 4; ++r)
          C[(size_t)(m0 + wr * 64 + m * 16 + g * 4 + r) * N +
            n0 + wc * 32 + n * 16 + lr] = f2bf(acc[m][n][r]);
  }
}

// ---------------- flash attention ----------------
// 1D grid of 1024 blocks, heavy-first: qt = 31-(n>>5), bh = n&31.
// 4 waves; wave w owns q rows [q0+16w, q0+16w+16). KVBLK=128.
// QKV packed [B*T][1536]: Q at h*64, K at 1024+kvh*64, V at 1280+kvh*64.
// LDS XOR-swizzled (byte ^= (row&7)<<4 within row). Defer-max THR=8.
__global__ __launch_bounds__(256) void attn_fused(
    const unsigned short* __restrict__ QKV, unsigned short* __restrict__ Y) {
  __shared__ unsigned short Kt[128 * 64];     // [kv][d], swizzled
  __shared__ unsigned short Vt[64 * 128];     // [d][kv], swizzled
  __shared__ unsigned short Pb[4][16 * 128];  // per-wave P, swizzled

  const int T = 2048, CS = 1536;
  int tid = threadIdx.x;
  int w = tid >> 6, l = tid & 63, g = l >> 4, lr = l & 15;
  int n = blockIdx.x;
  int qt = 31 - (n >> 5);              // heavy blocks first
  int bh = n & 31, b = bh >> 4, h = bh & 15, kvh = h >> 2;
  int q0 = qt * 64, qw = q0 + w * 16, qmax = q0 + 63;
  int sx = lr & 7;

  const unsigned short* Qp = QKV + (size_t)b * T * CS + h * 64;
  const unsigned short* Kp = QKV + (size_t)b * T * CS + 1024 + kvh * 64;
  const unsigned short* Vp = QKV + (size_t)b * T * CS + 1280 + kvh * 64;

  s16x8 qf[2];
#pragma unroll
  for (int ks = 0; ks < 2; ++ks)
    qf[ks] = *(const s16x8*)(Qp + (size_t)(qw + lr) * CS + ks * 32 + g * 8);

  f32x4 o[4] = {};
  float mrun[4], lrun[4];
#pragma unroll
  for (int r = 0; r < 4; ++r) { mrun[r] = -1e30f; lrun[r] = 0.f; }

  unsigned short* Pw = Pb[w];
  int ntiles = (qt >> 1) + 1;

  for (int it = 0; it < ntiles; ++it) {
    int kv0 = it * 128;
    // stage K [128][64]: linear LDS dest, pre-swizzled global source
#pragma unroll
    for (int i = 0; i < 4; ++i) {
      int c = i * 256 + tid;
      int row = c >> 3;
      int srcc = ((c & 7) ^ (row & 7)) * 8;
      async16(Kp + (size_t)(kv0 + row) * CS + srcc, (char*)Kt + c * 16);
    }
    // stage V transposed [64][128], swizzled write
#pragma unroll
    for (int i = 0; i < 4; ++i) {
      int c = i * 256 + tid;
      int kv = c & 127, d0 = (c >> 7) * 8;
      s16x8 vv = *(const s16x8*)(Vp + (size_t)(kv0 + kv) * CS + d0);
#pragma unroll
      for (int j = 0; j < 8; ++j)
        Vt[(d0 + j) * 128 + (kv ^ (j * 8))] = (unsigned short)vv[j];
    }
    __syncthreads();

    // S = Q K^T : rows = q (g*4+r), cols = kv (nf*16+lr); skip dead frags
    f32x4 s[8];
    __builtin_amdgcn_s_setprio(1);
#pragma unroll
    for (int nf = 0; nf < 8; ++nf) {
      if (kv0 + nf * 16 <= qmax) {           // wave-uniform
        f32x4 z = {};
#pragma unroll
        for (int ks = 0; ks < 2; ++ks) {
          s16x8 kf = *(const s16x8*)(Kt + (nf * 16 + lr) * 64 +
                                     ((ks * 4 + g) ^ sx) * 8);
          z = __builtin_amdgcn_mfma_f32_16x16x32_bf16(qf[ks], kf, z, 0, 0, 0);
        }
        s[nf] = z;
      } else {
        s[nf] = f32x4{-1e30f, -1e30f, -1e30f, -1e30f};
      }
    }
    __builtin_amdgcn_s_setprio(0);

    if (it == ntiles - 1) {   // diagonal tile: causal mask
#pragma unroll
      for (int nf = 0; nf < 8; ++nf) {
        int kvg = kv0 + nf * 16 + lr;
#pragma unroll
        for (int r = 0; r < 4; ++r)
          if (kvg > qw + g * 4 + r) s[nf][r] = -1e30f;
      }
    }

    // online softmax per row r; defer-max (THR=8 nat-log)
#pragma unroll
    for (int r = 0; r < 4; ++r) {
      float mt = s[0][r];
#pragma unroll
      for (int nf = 1; nf < 8; ++nf) mt = fmaxf(mt, s[nf][r]);
#pragma unroll
      for (int msk = 1; msk <= 8; msk <<= 1) mt = fmaxf(mt, __shfl_xor(mt, msk, 64));
      if (mt <= mrun[r] + 8.f) {
        // fast path: no rescale
        float psum = 0.f;
#pragma unroll
        for (int nf = 0; nf < 8; ++nf) {
          float p = exp2f((s[nf][r] - mrun[r]) * LOG2E);
          s[nf][r] = p;
          psum += p;
        }
#pragma unroll
        for (int msk = 1; msk <= 8; msk <<= 1) psum += __shfl_xor(psum, msk, 64);
        lrun[r] += psum;
      } else {
        float corr = exp2f((mrun[r] - mt) * LOG2E);
        float psum = 0.f;
#pragma unroll
        for (int nf = 0; nf < 8; ++nf) {
          float p = exp2f((s[nf][r] - mt) * LOG2E);
          s[nf][r] = p;
          psum += p;
        }
#pragma unroll
        for (int msk = 1; msk <= 8; msk <<= 1) psum += __shfl_xor(psum, msk, 64);
        lrun[r] = lrun[r] * corr + psum;
        mrun[r] = mt;
#pragma unroll
        for (int d0 = 0; d0 < 4; ++d0) o[d0][r] *= corr;
      }
    }

    // P -> per-wave LDS (swizzled), then re-read as A-fragments
#pragma unroll
    for (int nf = 0; nf < 8; ++nf)
#pragma unroll
      for (int r = 0; r < 4; ++r) {
        int prow = g * 4 + r;
        Pw[prow * 128 + ((nf * 16 + lr) ^ ((prow & 7) * 8))] = f2bf(s[nf][r]);
      }
    asm volatile("s_waitcnt lgkmcnt(0)" ::: "memory");
    __builtin_amdgcn_sched_barrier(0);   // rule #18

    __builtin_amdgcn_s_setprio(1);
#pragma unroll
    for (int ks = 0; ks < 4; ++ks) {
      if (kv0 + ks * 32 <= qmax) {         // wave-uniform: skip all-zero P
        s16x8 pf = *(const s16x8*)(Pw + lr * 128 + ((ks * 4 + g) ^ sx) * 8);
#pragma unroll
        for (int d0 = 0; d0 < 4; ++d0) {
          s16x8 vf = *(const s16x8*)(Vt + (d0 * 16 + lr) * 128 +
                                     ((ks * 4 + g) ^ sx) * 8);
          o[d0] = __builtin_amdgcn_mfma_f32_16x16x32_bf16(pf, vf, o[d0], 0, 0, 0);
        }
      }
    }
    __builtin_amdgcn_s_setprio(0);
    __syncthreads();
  }

#pragma unroll
  for (int r = 0; r < 4; ++r) {
    float inv = 1.f / lrun[r];
    size_t rowoff = (size_t)(b * T + qw + g * 4 + r) * 1024 + h * 64;
#pragma unroll
    for (int d0 = 0; d0 < 4; ++d0)
      Y[rowoff + d0 * 16 + lr] = f2bf(o[d0][r] * inv);
  }
}

// ---------------- launch ----------------

extern "C" void kernel_launch(void* const* d_in, const int* in_sizes, int n_in,
                              void* d_out, int out_size, void* d_ws, size_t ws_size,
                              hipStream_t stream) {
  const float* x    = (const float*)d_in[0];
  const float* cosb = (const float*)d_in[1];
  const float* sinb = (const float*)d_in[2];
  const float* Wq   = (const float*)d_in[3];
  const float* Wk   = (const float*)d_in[4];
  const float* Wv   = (const float*)d_in[5];
  const float* Wo   = (const float*)d_in[6];
  float* out = (float*)d_out;

  // Buffer map:
  //   d_out (16 MB): QKVb [4096][1536] bf16 = 12 MB  (dead at final gemm)
  //   d_ws: xb 0..8M | Wqkvt 8..11M | Wot 11..13M ; Yb aliases xb after attn
  char* ob = (char*)d_out;
  char* ws = (char*)d_ws;
  const size_t MB = 1024 * 1024;
  unsigned short* QKVb  = (unsigned short*)(ob);
  unsigned short* xb    = (unsigned short*)(ws);
  unsigned short* Wqkvt = (unsigned short*)(ws + 8 * MB);
  unsigned short* Wot   = (unsigned short*)(ws + 11 * MB);
  unsigned short* Yb    = xb;   // x-content dead after QKV gemm

  conv_f32_to_bf16<<<4096, 256, 0, stream>>>(x, xb, 4096 * 1024);
  // pack W_qkv^T rows: [0,1024) = Wq, [1024,1280) = Wk, [1280,1536) = Wv
  transpose_conv<<<dim3(32, 32), dim3(32, 8), 0, stream>>>(Wq, Wqkvt, 1024, 1024);
  transpose_conv<<<dim3(8, 32), dim3(32, 8), 0, stream>>>(Wk, Wqkvt + (size_t)1024 * 1024, 1024, 256);
  transpose_conv<<<dim3(8, 32), dim3(32, 8), 0, stream>>>(Wv, Wqkvt + (size_t)1280 * 1024, 1024, 256);
  transpose_conv<<<dim3(32, 32), dim3(32, 8), 0, stream>>>(Wo, Wot, 1024, 1024);

  // fused QKV projection: [4096][1536] bf16
  gemm_bt<<<dim3(24, 32), 256, 0, stream>>>(xb, Wqkvt, QKVb, 4096, 1536, 1024, 0);

  // RoPE on Q (x0.125) + K in one pass
  rope_qk<<<10240, 256, 0, stream>>>(QKVb, cosb, sinb);

  // attention -> Yb bf16 [B*T][1024]
  attn_fused<<<dim3(1024), 256, 0, stream>>>(QKVb, Yb);

  // output projection (fp32, overwrites d_out)
  gemm_bt<<<dim3(16, 32), 256, 0, stream>>>(Yb, Wot, out, 4096, 1024, 1024, 1);
}

// Round 8
// 142.110 us; speedup vs baseline: 2.1610x; 1.1611x over previous
//
#include <hip/hip_runtime.h>
#include <hip/hip_bf16.h>

// Fused causal self-attention (GQA) for MI355X/gfx950.
// Shapes: B=2, T=2048, C=1024, H=16, Hkv=4, D=64.
// Round 8: fix R7's NaN — deferred V-staging chunk B decoded c=256+tid wrong
// (dB = dA+16 -> double-write {16,24}, never-write {48,56} -> uninit LDS ->
// NaN via PV MFMA). Correct: dB = dA+32. Rest of R7 unchanged.

typedef __attribute__((ext_vector_type(8))) short s16x8;   // 8 x bf16 raw
typedef __attribute__((ext_vector_type(4))) float f32x4;
typedef __attribute__((ext_vector_type(4))) unsigned short u16x4;

#define LOG2E 1.44269504088896340736f

__device__ __forceinline__ float bf2f(unsigned short u) {
  unsigned int i = ((unsigned int)u) << 16;
  return __builtin_bit_cast(float, i);
}
__device__ __forceinline__ unsigned short f2bf(float f) {
  unsigned int i = __builtin_bit_cast(unsigned int, f);
  i += 0x7fffu + ((i >> 16) & 1u);   // RNE
  return (unsigned short)(i >> 16);
}

__device__ __forceinline__ void async16(const void* g, void* l) {
  __builtin_amdgcn_global_load_lds(
      (const __attribute__((address_space(1))) void*)g,
      (__attribute__((address_space(3))) void*)l, 16, 0, 0);
}

// ---------------- prep kernels ----------------

__global__ void conv_f32_to_bf16(const float* __restrict__ in,
                                 unsigned short* __restrict__ out, int n) {
  int i = (blockIdx.x * blockDim.x + threadIdx.x) * 4;
  if (i + 3 < n) {
    float4 v = *(const float4*)(in + i);
    u16x4 o = { f2bf(v.x), f2bf(v.y), f2bf(v.z), f2bf(v.w) };
    *(u16x4*)(out + i) = o;
  }
}

// W [K][N] fp32 -> Wt [N][K] bf16
__global__ void transpose_conv(const float* __restrict__ W,
                               unsigned short* __restrict__ Wt, int K, int N) {
  __shared__ float tile[32][33];
  int n0 = blockIdx.x * 32, k0 = blockIdx.y * 32;
  int tx = threadIdx.x, ty = threadIdx.y;
  for (int i = ty; i < 32; i += 8)
    tile[i][tx] = W[(size_t)(k0 + i) * N + n0 + tx];
  __syncthreads();
  for (int i = ty; i < 32; i += 8)
    Wt[(size_t)(n0 + i) * K + k0 + tx] = f2bf(tile[tx][i]);
}

// RoPE on packed QKV [4096][1536]: heads 0..15 = Q (scaled 0.125),
// heads 16..19 = K at col offset 1024. t = row % 2048.
__global__ void rope_qk(unsigned short* __restrict__ QKV,
                        const float* __restrict__ cosb,
                        const float* __restrict__ sinb) {
  int idx = blockIdx.x * blockDim.x + threadIdx.x;
  int d = idx & 31;
  int hh = (idx >> 5) % 20;
  int row = idx / (32 * 20);
  int t = row & 2047;
  size_t base;
  float mul;
  if (hh < 16) { base = (size_t)row * 1536 + hh * 64 + d;               mul = 0.125f; }
  else         { base = (size_t)row * 1536 + 1024 + (hh - 16) * 64 + d; mul = 1.0f;   }
  float x1 = bf2f(QKV[base]), x2 = bf2f(QKV[base + 32]);
  float c = cosb[t * 32 + d], s = sinb[t * 32 + d];
  QKV[base]      = f2bf((x1 * c + x2 * s) * mul);
  QKV[base + 32] = f2bf((-x1 * s + x2 * c) * mul);
}

// ---------------- GEMM: C[M,N] = A[M,K] * Bt[N,K]^T ----------------
// 128x64 tile, BK=32, 4 waves (2x2), wave = 64x32 via 4x2 16x16x32 MFMA.
__global__ __launch_bounds__(256) void gemm_bt(
    const unsigned short* __restrict__ A, const unsigned short* __restrict__ Bt,
    void* __restrict__ Cp, int M, int N, int K, int c_f32) {
  __shared__ unsigned short As[128 * 32];
  __shared__ unsigned short Bs[64 * 32];
  int tid = threadIdx.x;
  int w = tid >> 6, l = tid & 63, g = l >> 4, lr = l & 15;
  int wr = w >> 1, wc = w & 1;
  int m0 = blockIdx.y * 128, n0 = blockIdx.x * 64;
  int sk = lr & 3;   // fragment-read swizzle key

  f32x4 acc[4][2] = {};

  for (int k0 = 0; k0 < K; k0 += 32) {
#pragma unroll
    for (int i = 0; i < 2; ++i) {
      int c = i * 256 + tid;
      int row = c >> 2, srcc = ((c & 3) ^ (row & 3)) * 8;
      async16(A + (size_t)(m0 + row) * K + k0 + srcc, (char*)As + c * 16);
    }
    {
      int c = tid;
      int row = c >> 2, srcc = ((c & 3) ^ (row & 3)) * 8;
      async16(Bt + (size_t)(n0 + row) * K + k0 + srcc, (char*)Bs + c * 16);
    }
    __syncthreads();

    s16x8 af[4], bfr[2];
#pragma unroll
    for (int m = 0; m < 4; ++m)
      af[m] = *(const s16x8*)(As + (wr * 64 + m * 16 + lr) * 32 + (g ^ sk) * 8);
#pragma unroll
    for (int n = 0; n < 2; ++n)
      bfr[n] = *(const s16x8*)(Bs + (wc * 32 + n * 16 + lr) * 32 + (g ^ sk) * 8);
#pragma unroll
    for (int m = 0; m < 4; ++m)
#pragma unroll
      for (int n = 0; n < 2; ++n)
        acc[m][n] = __builtin_amdgcn_mfma_f32_16x16x32_bf16(af[m], bfr[n],
                                                            acc[m][n], 0, 0, 0);
    __syncthreads();
  }

  // C/D layout: row = (l>>4)*4 + r, col = l&15  [HW-verified]
  if (c_f32) {
    float* C = (float*)Cp;
#pragma unroll
    for (int m = 0; m < 4; ++m)
#pragma unroll
      for (int n = 0; n < 2; ++n)
#pragma unroll
        for (int r = 0; r < 4; ++r)
          C[(size_t)(m0 + wr * 64 + m * 16 + g * 4 + r) * N +
            n0 + wc * 32 + n * 16 + lr] = acc[m][n][r];
  } else {
    unsigned short* C = (unsigned short*)Cp;
#pragma unroll
    for (int m = 0; m < 4; ++m)
#pragma unroll
      for (int n = 0; n < 2; ++n)
#pragma unroll
        for (int r = 0; r < 4; ++r)
          C[(size_t)(m0 + wr * 64 + m * 16 + g * 4 + r) * N +
            n0 + wc * 32 + n * 16 + lr] = f2bf(acc[m][n][r]);
  }
}

// ---------------- flash attention (swapped QK^T) ----------------
// 1D grid 1024 blocks heavy-first: qt = 31-(n>>5), bh = n&31. 4 waves; wave w
// owns q rows [q0+16w, q0+16w+16). KVBLK=64, double-buffered K/V LDS.
// Swapped S^T = mfma(K,Q): lane (g,lr) holds S[q=qw+lr][kv=nf*16+g*4+r].
__global__ __launch_bounds__(256) void attn_fused(
    const unsigned short* __restrict__ QKV, unsigned short* __restrict__ Y) {
  __shared__ unsigned short Kt[2][64 * 64];   // [kv][d], swizzled
  __shared__ unsigned short Vt[2][64 * 64];   // [d][kv], swizzled
  __shared__ unsigned short Pb[4][16 * 64];   // per-wave P [q][kv], swizzled

  const int T = 2048, CS = 1536;
  int tid = threadIdx.x;
  int w = tid >> 6, l = tid & 63, g = l >> 4, lr = l & 15;
  int n = blockIdx.x;
  int qt = 31 - (n >> 5);              // heavy blocks first
  int bh = n & 31, b = bh >> 4, h = bh & 15, kvh = h >> 2;
  int q0 = qt * 64, qw = q0 + w * 16;
  int sx = lr & 7;
  int q_mine = qw + lr;                // this lane's q-row (swapped layout)

  const unsigned short* Qp = QKV + (size_t)b * T * CS + h * 64;
  const unsigned short* Kp = QKV + (size_t)b * T * CS + 1024 + kvh * 64;
  const unsigned short* Vp = QKV + (size_t)b * T * CS + 1280 + kvh * 64;

  s16x8 qf[2];
#pragma unroll
  for (int ks = 0; ks < 2; ++ks)
    qf[ks] = *(const s16x8*)(Qp + (size_t)q_mine * CS + ks * 32 + g * 8);

  f32x4 o[4] = {};
  float mrun = -1e30f, lrun = 0.f;     // per-lane: state of q-row q_mine

  unsigned short* Pw = Pb[w];
  int ntiles = qt + 1;

  // ---- prologue: stage tile 0 into buffer 0 ----
#pragma unroll
  for (int i = 0; i < 2; ++i) {
    int c = i * 256 + tid;
    int row = c >> 3, srcc = ((c & 7) ^ (row & 7)) * 8;
    async16(Kp + (size_t)row * CS + srcc, (char*)(&Kt[0][0]) + c * 16);
  }
#pragma unroll
  for (int i = 0; i < 2; ++i) {
    int c = i * 256 + tid;
    int kv = c & 63, d0v = (c >> 6) * 8;
    s16x8 vv = *(const s16x8*)(Vp + (size_t)kv * CS + d0v);
#pragma unroll
    for (int j = 0; j < 8; ++j)
      Vt[0][(d0v + j) * 64 + (kv ^ (j * 8))] = (unsigned short)vv[j];
  }
  __syncthreads();

  int cur = 0;
  for (int it = 0; it < ntiles; ++it) {
    int kv0 = it * 64;
    bool hasnext = (it + 1 < ntiles);

    // ---- T14 stage: issue next tile's K (async->LDS) and V (->regs) ----
    // c = tid:      kv = tid&63, d-chunk = (tid>>6)*8      in {0,8,16,24}
    // c = 256+tid:  kv = tid&63, d-chunk = (tid>>6)*8 + 32 in {32,40,48,56}
    s16x8 vvA, vvB;
    int kvA = tid & 63, dA = (tid >> 6) * 8;
    int dB = dA + 32;                  // R8 fix (was dA+16: uninit LDS -> NaN)
    if (hasnext) {
      int kvn = kv0 + 64;
#pragma unroll
      for (int i = 0; i < 2; ++i) {
        int c = i * 256 + tid;
        int row = c >> 3, srcc = ((c & 7) ^ (row & 7)) * 8;
        async16(Kp + (size_t)(kvn + row) * CS + srcc,
                (char*)(&Kt[cur ^ 1][0]) + c * 16);
      }
      vvA = *(const s16x8*)(Vp + (size_t)(kvn + kvA) * CS + dA);
      vvB = *(const s16x8*)(Vp + (size_t)(kvn + kvA) * CS + dB);
    }

    // ---- S^T = K Q^T on buf cur: lane holds S[q_mine][kv=nf*16+g*4+r] ----
    const unsigned short* Kc = &Kt[cur][0];
    const unsigned short* Vc = &Vt[cur][0];
    f32x4 s[4];
    __builtin_amdgcn_s_setprio(1);
#pragma unroll
    for (int nf = 0; nf < 4; ++nf) {
      f32x4 z = {};
#pragma unroll
      for (int ks = 0; ks < 2; ++ks) {
        s16x8 kf = *(const s16x8*)(Kc + (nf * 16 + lr) * 64 +
                                   ((ks * 4 + g) ^ sx) * 8);
        z = __builtin_amdgcn_mfma_f32_16x16x32_bf16(kf, qf[ks], z, 0, 0, 0);
      }
      s[nf] = z;
    }
    __builtin_amdgcn_s_setprio(0);

    if (it == ntiles - 1) {   // diagonal tile: causal mask (swapped layout)
#pragma unroll
      for (int nf = 0; nf < 4; ++nf)
#pragma unroll
        for (int r = 0; r < 4; ++r)
          if (kv0 + nf * 16 + g * 4 + r > q_mine) s[nf][r] = -1e30f;
    }

    // ---- softmax: all 16 values belong to q_mine; reduce in-lane + 2 shfl ----
    float mt = s[0][0];
#pragma unroll
    for (int nf = 0; nf < 4; ++nf)
#pragma unroll
      for (int r = 0; r < 4; ++r) mt = fmaxf(mt, s[nf][r]);
    mt = fmaxf(mt, __shfl_xor(mt, 16, 64));
    mt = fmaxf(mt, __shfl_xor(mt, 32, 64));

    if (__any(mt > mrun + 8.f)) {      // wave-uniform rescale (defer-max)
      float mnew = fmaxf(mrun, mt);
      float corr = exp2f((mrun - mnew) * LOG2E);
      float psum = 0.f;
#pragma unroll
      for (int nf = 0; nf < 4; ++nf)
#pragma unroll
        for (int r = 0; r < 4; ++r) {
          float p = exp2f((s[nf][r] - mnew) * LOG2E);
          s[nf][r] = p;
          psum += p;
        }
      psum += __shfl_xor(psum, 16, 64);
      psum += __shfl_xor(psum, 32, 64);
      lrun = lrun * corr + psum;
      mrun = mnew;
#pragma unroll
      for (int r = 0; r < 4; ++r) {    // redistribute corr to o-rows
        float cr = __shfl(corr, g * 4 + r, 64);
#pragma unroll
        for (int d0 = 0; d0 < 4; ++d0) o[d0][r] *= cr;
      }
    } else {                           // fast path: no rescale
      float psum = 0.f;
#pragma unroll
      for (int nf = 0; nf < 4; ++nf)
#pragma unroll
        for (int r = 0; r < 4; ++r) {
          float p = exp2f((s[nf][r] - mrun) * LOG2E);
          s[nf][r] = p;
          psum += p;
        }
      psum += __shfl_xor(psum, 16, 64);
      psum += __shfl_xor(psum, 32, 64);
      lrun += psum;
    }

    // ---- P -> LDS [q][kv] (row = lr now), swizzled; then PV ----
#pragma unroll
    for (int nf = 0; nf < 4; ++nf)
#pragma unroll
      for (int r = 0; r < 4; ++r) {
        int col = nf * 16 + g * 4 + r;
        Pw[lr * 64 + (col ^ (sx * 8))] = f2bf(s[nf][r]);
      }
    asm volatile("s_waitcnt lgkmcnt(0)" ::: "memory");
    __builtin_amdgcn_sched_barrier(0);   // rule #18

    s16x8 pf[2];
#pragma unroll
    for (int ks = 0; ks < 2; ++ks)
      pf[ks] = *(const s16x8*)(Pw + lr * 64 + ((ks * 4 + g) ^ sx) * 8);
    __builtin_amdgcn_s_setprio(1);
#pragma unroll
    for (int d0 = 0; d0 < 4; ++d0)
#pragma unroll
      for (int ks = 0; ks < 2; ++ks) {
        s16x8 vf = *(const s16x8*)(Vc + (d0 * 16 + lr) * 64 +
                                   ((ks * 4 + g) ^ sx) * 8);
        o[d0] = __builtin_amdgcn_mfma_f32_16x16x32_bf16(pf[ks], vf, o[d0], 0, 0, 0);
      }
    __builtin_amdgcn_s_setprio(0);

    // ---- write staged V regs -> next buffer (after PV; other buffer, safe) ----
    if (hasnext) {
#pragma unroll
      for (int j = 0; j < 8; ++j)
        Vt[cur ^ 1][(dA + j) * 64 + (kvA ^ (j * 8))] = (unsigned short)vvA[j];
#pragma unroll
      for (int j = 0; j < 8; ++j)
        Vt[cur ^ 1][(dB + j) * 64 + (kvA ^ (j * 8))] = (unsigned short)vvB[j];
    }
    __syncthreads();   // drains vmcnt (K async) + lgkm (V writes); swap buffers
    cur ^= 1;
  }

  // o rows are q-local g*4+r; lrun lives at lane (*,lr=g*4+r) -> shuffle
#pragma unroll
  for (int r = 0; r < 4; ++r) {
    float lv = __shfl(lrun, g * 4 + r, 64);
    float inv = 1.f / lv;
    size_t rowoff = (size_t)(b * T + qw + g * 4 + r) * 1024 + h * 64;
#pragma unroll
    for (int d0 = 0; d0 < 4; ++d0)
      Y[rowoff + d0 * 16 + lr] = f2bf(o[d0][r] * inv);
  }
}

// ---------------- launch ----------------

extern "C" void kernel_launch(void* const* d_in, const int* in_sizes, int n_in,
                              void* d_out, int out_size, void* d_ws, size_t ws_size,
                              hipStream_t stream) {
  const float* x    = (const float*)d_in[0];
  const float* cosb = (const float*)d_in[1];
  const float* sinb = (const float*)d_in[2];
  const float* Wq   = (const float*)d_in[3];
  const float* Wk   = (const float*)d_in[4];
  const float* Wv   = (const float*)d_in[5];
  const float* Wo   = (const float*)d_in[6];
  float* out = (float*)d_out;

  // Buffer map:
  //   d_out (16 MB): QKVb [4096][1536] bf16 = 12 MB  (dead at final gemm)
  //   d_ws: xb 0..8M | Wqkvt 8..11M | Wot 11..13M ; Yb aliases xb after attn
  char* ob = (char*)d_out;
  char* ws = (char*)d_ws;
  const size_t MB = 1024 * 1024;
  unsigned short* QKVb  = (unsigned short*)(ob);
  unsigned short* xb    = (unsigned short*)(ws);
  unsigned short* Wqkvt = (unsigned short*)(ws + 8 * MB);
  unsigned short* Wot   = (unsigned short*)(ws + 11 * MB);
  unsigned short* Yb    = xb;   // x-content dead after QKV gemm

  conv_f32_to_bf16<<<4096, 256, 0, stream>>>(x, xb, 4096 * 1024);
  // pack W_qkv^T rows: [0,1024) = Wq, [1024,1280) = Wk, [1280,1536) = Wv
  transpose_conv<<<dim3(32, 32), dim3(32, 8), 0, stream>>>(Wq, Wqkvt, 1024, 1024);
  transpose_conv<<<dim3(8, 32), dim3(32, 8), 0, stream>>>(Wk, Wqkvt + (size_t)1024 * 1024, 1024, 256);
  transpose_conv<<<dim3(8, 32), dim3(32, 8), 0, stream>>>(Wv, Wqkvt + (size_t)1280 * 1024, 1024, 256);
  transpose_conv<<<dim3(32, 32), dim3(32, 8), 0, stream>>>(Wo, Wot, 1024, 1024);

  // fused QKV projection: [4096][1536] bf16
  gemm_bt<<<dim3(24, 32), 256, 0, stream>>>(xb, Wqkvt, QKVb, 4096, 1536, 1024, 0);

  // RoPE on Q (x0.125) + K in one pass
  rope_qk<<<10240, 256, 0, stream>>>(QKVb, cosb, sinb);

  // attention -> Yb bf16 [B*T][1024]
  attn_fused<<<dim3(1024), 256, 0, stream>>>(QKVb, Yb);

  // output projection (fp32, overwrites d_out)
  gemm_bt<<<dim3(16, 32), 256, 0, stream>>>(Yb, Wot, out, 4096, 1024, 1024, 1);
}

// Round 9
// 132.673 us; speedup vs baseline: 2.3147x; 1.0711x over previous
//
#include <hip/hip_runtime.h>
#include <hip/hip_bf16.h>

// Fused causal self-attention (GQA) for MI355X/gfx950.
// Shapes: B=2, T=2048, C=1024, H=16, Hkv=4, D=64.
// Round 9: (1) balanced q-tile pairing — block = pair (31-i, i), uniform 33
// tile-iters, 512 blocks; (2) P-write via 4x ds_write_b64 (was 16x b16, the
// R8 conflict source); (3) gemm BK=64 with full lr&7 swizzle (R5-proven
// conflict-free geometry), halved barriers.

typedef __attribute__((ext_vector_type(8))) short s16x8;   // 8 x bf16 raw
typedef __attribute__((ext_vector_type(4))) float f32x4;
typedef __attribute__((ext_vector_type(4))) unsigned short u16x4;

#define LOG2E 1.44269504088896340736f

__device__ __forceinline__ float bf2f(unsigned short u) {
  unsigned int i = ((unsigned int)u) << 16;
  return __builtin_bit_cast(float, i);
}
__device__ __forceinline__ unsigned short f2bf(float f) {
  unsigned int i = __builtin_bit_cast(unsigned int, f);
  i += 0x7fffu + ((i >> 16) & 1u);   // RNE
  return (unsigned short)(i >> 16);
}

__device__ __forceinline__ void async16(const void* g, void* l) {
  __builtin_amdgcn_global_load_lds(
      (const __attribute__((address_space(1))) void*)g,
      (__attribute__((address_space(3))) void*)l, 16, 0, 0);
}

// ---------------- prep kernels ----------------

__global__ void conv_f32_to_bf16(const float* __restrict__ in,
                                 unsigned short* __restrict__ out, int n) {
  int i = (blockIdx.x * blockDim.x + threadIdx.x) * 4;
  if (i + 3 < n) {
    float4 v = *(const float4*)(in + i);
    u16x4 o = { f2bf(v.x), f2bf(v.y), f2bf(v.z), f2bf(v.w) };
    *(u16x4*)(out + i) = o;
  }
}

// W [K][N] fp32 -> Wt [N][K] bf16
__global__ void transpose_conv(const float* __restrict__ W,
                               unsigned short* __restrict__ Wt, int K, int N) {
  __shared__ float tile[32][33];
  int n0 = blockIdx.x * 32, k0 = blockIdx.y * 32;
  int tx = threadIdx.x, ty = threadIdx.y;
  for (int i = ty; i < 32; i += 8)
    tile[i][tx] = W[(size_t)(k0 + i) * N + n0 + tx];
  __syncthreads();
  for (int i = ty; i < 32; i += 8)
    Wt[(size_t)(n0 + i) * K + k0 + tx] = f2bf(tile[tx][i]);
}

// RoPE on packed QKV [4096][1536]: heads 0..15 = Q (scaled 0.125),
// heads 16..19 = K at col offset 1024. t = row % 2048.
__global__ void rope_qk(unsigned short* __restrict__ QKV,
                        const float* __restrict__ cosb,
                        const float* __restrict__ sinb) {
  int idx = blockIdx.x * blockDim.x + threadIdx.x;
  int d = idx & 31;
  int hh = (idx >> 5) % 20;
  int row = idx / (32 * 20);
  int t = row & 2047;
  size_t base;
  float mul;
  if (hh < 16) { base = (size_t)row * 1536 + hh * 64 + d;               mul = 0.125f; }
  else         { base = (size_t)row * 1536 + 1024 + (hh - 16) * 64 + d; mul = 1.0f;   }
  float x1 = bf2f(QKV[base]), x2 = bf2f(QKV[base + 32]);
  float c = cosb[t * 32 + d], s = sinb[t * 32 + d];
  QKV[base]      = f2bf((x1 * c + x2 * s) * mul);
  QKV[base + 32] = f2bf((-x1 * s + x2 * c) * mul);
}

// ---------------- GEMM: C[M,N] = A[M,K] * Bt[N,K]^T ----------------
// 128x64 tile, BK=64, 4 waves (2x2), wave = 64x32 via 4x2x2 16x16x32 MFMA.
// LDS rows are 64 elems (128 B); full 3-bit XOR swizzle via pre-swizzled
// global source (same key lr&7 on A and B -> k-mapping cancels).
__global__ __launch_bounds__(256) void gemm_bt(
    const unsigned short* __restrict__ A, const unsigned short* __restrict__ Bt,
    void* __restrict__ Cp, int M, int N, int K, int c_f32) {
  __shared__ unsigned short As[128 * 64];   // 16 KB
  __shared__ unsigned short Bs[64 * 64];    // 8 KB
  int tid = threadIdx.x;
  int w = tid >> 6, l = tid & 63, g = l >> 4, lr = l & 15;
  int wr = w >> 1, wc = w & 1;
  int m0 = blockIdx.y * 128, n0 = blockIdx.x * 64;
  int sk = lr & 7;   // fragment-read swizzle key

  f32x4 acc[4][2] = {};

  for (int k0 = 0; k0 < K; k0 += 64) {
#pragma unroll
    for (int i = 0; i < 4; ++i) {
      int c = i * 256 + tid;             // 16B unit index, 8 units/row
      int row = c >> 3, srcu = ((c & 7) ^ (row & 7)) * 8;
      async16(A + (size_t)(m0 + row) * K + k0 + srcu, (char*)As + c * 16);
    }
#pragma unroll
    for (int i = 0; i < 2; ++i) {
      int c = i * 256 + tid;
      int row = c >> 3, srcu = ((c & 7) ^ (row & 7)) * 8;
      async16(Bt + (size_t)(n0 + row) * K + k0 + srcu, (char*)Bs + c * 16);
    }
    __syncthreads();

    s16x8 af[2][4], bfr[2][2];
#pragma unroll
    for (int ks = 0; ks < 2; ++ks) {
#pragma unroll
      for (int m = 0; m < 4; ++m)
        af[ks][m] = *(const s16x8*)(As + (wr * 64 + m * 16 + lr) * 64 +
                                    ((ks * 4 + g) ^ sk) * 8);
#pragma unroll
      for (int n = 0; n < 2; ++n)
        bfr[ks][n] = *(const s16x8*)(Bs + (wc * 32 + n * 16 + lr) * 64 +
                                     ((ks * 4 + g) ^ sk) * 8);
    }
#pragma unroll
    for (int ks = 0; ks < 2; ++ks)
#pragma unroll
      for (int m = 0; m < 4; ++m)
#pragma unroll
        for (int n = 0; n < 2; ++n)
          acc[m][n] = __builtin_amdgcn_mfma_f32_16x16x32_bf16(
              af[ks][m], bfr[ks][n], acc[m][n], 0, 0, 0);
    __syncthreads();
  }

  // C/D layout: row = (l>>4)*4 + r, col = l&15  [HW-verified]
  if (c_f32) {
    float* C = (float*)Cp;
#pragma unroll
    for (int m = 0; m < 4; ++m)
#pragma unroll
      for (int n = 0; n < 2; ++n)
#pragma unroll
        for (int r = 0; r < 4; ++r)
          C[(size_t)(m0 + wr * 64 + m * 16 + g * 4 + r) * N +
            n0 + wc * 32 + n * 16 + lr] = acc[m][n][r];
  } else {
    unsigned short* C = (unsigned short*)Cp;
#pragma unroll
    for (int m = 0; m < 4; ++m)
#pragma unroll
      for (int n = 0; n < 2; ++n)
#pragma unroll
        for (int r = 0; r < 4; ++r)
          C[(size_t)(m0 + wr * 64 + m * 16 + g * 4 + r) * N +
            n0 + wc * 32 + n * 16 + lr] = f2bf(acc[m][n][r]);
  }
}

// ---------------- flash attention (swapped QK^T, paired q-tiles) ----------------
// 512 blocks; block n handles q-tile pair (31-ip, ip), ip = n>>5 -> uniform
// 33 tile-iters/block, 66/CU. 4 waves; wave w owns q rows [qt*64+16w, +16).
// KVBLK=64, double-buffered K/V. Lane (g,lr) holds S[q=qw+lr][kv=nf*16+g*4+r].
__global__ __launch_bounds__(256) void attn_fused(
    const unsigned short* __restrict__ QKV, unsigned short* __restrict__ Y) {
  __shared__ unsigned short Kt[2][64 * 64];   // [kv][d], swizzled
  __shared__ unsigned short Vt[2][64 * 64];   // [d][kv], swizzled
  __shared__ unsigned short Pb[4][16 * 64];   // per-wave P [q][kv], swizzled

  const int T = 2048, CS = 1536;
  int tid = threadIdx.x;
  int w = tid >> 6, l = tid & 63, g = l >> 4, lr = l & 15;
  int n = blockIdx.x;
  int ip = n >> 5;                     // pair index 0..15
  int bh = n & 31, b = bh >> 4, h = bh & 15, kvh = h >> 2;
  int sx = lr & 7;

  const unsigned short* Qp = QKV + (size_t)b * T * CS + h * 64;
  const unsigned short* Kp = QKV + (size_t)b * T * CS + 1024 + kvh * 64;
  const unsigned short* Vp = QKV + (size_t)b * T * CS + 1280 + kvh * 64;
  unsigned short* Pw = Pb[w];

  // V steady-state stage decode: c=tid -> d in {0..24}; c=256+tid -> d+32
  int kvA = tid & 63, dA = (tid >> 6) * 8, dB = dA + 32;

  for (int pass = 0; pass < 2; ++pass) {
    int qt = pass == 0 ? (31 - ip) : ip;
    int qw = qt * 64 + w * 16;
    int q_mine = qw + lr;              // this lane's q-row

    s16x8 qf[2];
#pragma unroll
    for (int ks = 0; ks < 2; ++ks)
      qf[ks] = *(const s16x8*)(Qp + (size_t)q_mine * CS + ks * 32 + g * 8);

    f32x4 o[4] = {};
    float mrun = -1e30f, lrun = 0.f;
    int ntiles = qt + 1;

    // ---- prologue: stage tile 0 into buffer 0 ----
#pragma unroll
    for (int i = 0; i < 2; ++i) {
      int c = i * 256 + tid;
      int row = c >> 3, srcc = ((c & 7) ^ (row & 7)) * 8;
      async16(Kp + (size_t)row * CS + srcc, (char*)(&Kt[0][0]) + c * 16);
    }
#pragma unroll
    for (int i = 0; i < 2; ++i) {
      int c = i * 256 + tid;
      int kv = c & 63, d0v = (c >> 6) * 8;
      s16x8 vv = *(const s16x8*)(Vp + (size_t)kv * CS + d0v);
#pragma unroll
      for (int j = 0; j < 8; ++j)
        Vt[0][(d0v + j) * 64 + (kv ^ (j * 8))] = (unsigned short)vv[j];
    }
    __syncthreads();

    int cur = 0;
    for (int it = 0; it < ntiles; ++it) {
      int kv0 = it * 64;
      bool hasnext = (it + 1 < ntiles);

      // ---- T14 stage: issue next tile's K (async->LDS) and V (->regs) ----
      s16x8 vvA, vvB;
      if (hasnext) {
        int kvn = kv0 + 64;
#pragma unroll
        for (int i = 0; i < 2; ++i) {
          int c = i * 256 + tid;
          int row = c >> 3, srcc = ((c & 7) ^ (row & 7)) * 8;
          async16(Kp + (size_t)(kvn + row) * CS + srcc,
                  (char*)(&Kt[cur ^ 1][0]) + c * 16);
        }
        vvA = *(const s16x8*)(Vp + (size_t)(kvn + kvA) * CS + dA);
        vvB = *(const s16x8*)(Vp + (size_t)(kvn + kvA) * CS + dB);
      }

      // ---- S^T = K Q^T: lane holds S[q_mine][kv = nf*16 + g*4 + r] ----
      const unsigned short* Kc = &Kt[cur][0];
      const unsigned short* Vc = &Vt[cur][0];
      f32x4 s[4];
      __builtin_amdgcn_s_setprio(1);
#pragma unroll
      for (int nf = 0; nf < 4; ++nf) {
        f32x4 z = {};
#pragma unroll
        for (int ks = 0; ks < 2; ++ks) {
          s16x8 kf = *(const s16x8*)(Kc + (nf * 16 + lr) * 64 +
                                     ((ks * 4 + g) ^ sx) * 8);
          z = __builtin_amdgcn_mfma_f32_16x16x32_bf16(kf, qf[ks], z, 0, 0, 0);
        }
        s[nf] = z;
      }
      __builtin_amdgcn_s_setprio(0);

      if (it == ntiles - 1) {   // diagonal tile: causal mask
#pragma unroll
        for (int nf = 0; nf < 4; ++nf)
#pragma unroll
          for (int r = 0; r < 4; ++r)
            if (kv0 + nf * 16 + g * 4 + r > q_mine) s[nf][r] = -1e30f;
      }

      // ---- softmax: 16 in-lane values + 2 shuffles ----
      float mt = s[0][0];
#pragma unroll
      for (int nf = 0; nf < 4; ++nf)
#pragma unroll
        for (int r = 0; r < 4; ++r) mt = fmaxf(mt, s[nf][r]);
      mt = fmaxf(mt, __shfl_xor(mt, 16, 64));
      mt = fmaxf(mt, __shfl_xor(mt, 32, 64));

      if (__any(mt > mrun + 8.f)) {    // wave-uniform rescale (defer-max)
        float mnew = fmaxf(mrun, mt);
        float corr = exp2f((mrun - mnew) * LOG2E);
        float psum = 0.f;
#pragma unroll
        for (int nf = 0; nf < 4; ++nf)
#pragma unroll
          for (int r = 0; r < 4; ++r) {
            float p = exp2f((s[nf][r] - mnew) * LOG2E);
            s[nf][r] = p;
            psum += p;
          }
        psum += __shfl_xor(psum, 16, 64);
        psum += __shfl_xor(psum, 32, 64);
        lrun = lrun * corr + psum;
        mrun = mnew;
#pragma unroll
        for (int r = 0; r < 4; ++r) {
          float cr = __shfl(corr, g * 4 + r, 64);
#pragma unroll
          for (int d0 = 0; d0 < 4; ++d0) o[d0][r] *= cr;
        }
      } else {                         // fast path: no rescale
        float psum = 0.f;
#pragma unroll
        for (int nf = 0; nf < 4; ++nf)
#pragma unroll
          for (int r = 0; r < 4; ++r) {
            float p = exp2f((s[nf][r] - mrun) * LOG2E);
            s[nf][r] = p;
            psum += p;
          }
        psum += __shfl_xor(psum, 16, 64);
        psum += __shfl_xor(psum, 32, 64);
        lrun += psum;
      }

      // ---- P -> LDS [q=lr][kv], packed b64 writes (r 0..3 contiguous) ----
#pragma unroll
      for (int nf = 0; nf < 4; ++nf) {
        u16x4 pv = { f2bf(s[nf][0]), f2bf(s[nf][1]),
                     f2bf(s[nf][2]), f2bf(s[nf][3]) };
        *(u16x4*)(Pw + lr * 64 + ((nf * 16 + g * 4) ^ (sx * 8))) = pv;
      }
      asm volatile("s_waitcnt lgkmcnt(0)" ::: "memory");
      __builtin_amdgcn_sched_barrier(0);   // rule #18

      s16x8 pf[2];
#pragma unroll
      for (int ks = 0; ks < 2; ++ks)
        pf[ks] = *(const s16x8*)(Pw + lr * 64 + ((ks * 4 + g) ^ sx) * 8);
      __builtin_amdgcn_s_setprio(1);
#pragma unroll
      for (int d0 = 0; d0 < 4; ++d0)
#pragma unroll
        for (int ks = 0; ks < 2; ++ks) {
          s16x8 vf = *(const s16x8*)(Vc + (d0 * 16 + lr) * 64 +
                                     ((ks * 4 + g) ^ sx) * 8);
          o[d0] = __builtin_amdgcn_mfma_f32_16x16x32_bf16(pf[ks], vf, o[d0], 0, 0, 0);
        }
      __builtin_amdgcn_s_setprio(0);

      // ---- write staged V regs -> back buffer ----
      if (hasnext) {
#pragma unroll
        for (int j = 0; j < 8; ++j)
          Vt[cur ^ 1][(dA + j) * 64 + (kvA ^ (j * 8))] = (unsigned short)vvA[j];
#pragma unroll
        for (int j = 0; j < 8; ++j)
          Vt[cur ^ 1][(dB + j) * 64 + (kvA ^ (j * 8))] = (unsigned short)vvB[j];
      }
      __syncthreads();   // drains vmcnt (K async) + lgkm (V writes)
      cur ^= 1;
    }

    // ---- epilogue: o rows are g*4+r; lrun lives at lane (*, lr=g*4+r) ----
#pragma unroll
    for (int r = 0; r < 4; ++r) {
      float lv = __shfl(lrun, g * 4 + r, 64);
      float inv = 1.f / lv;
      size_t rowoff = (size_t)(b * T + qw + g * 4 + r) * 1024 + h * 64;
#pragma unroll
      for (int d0 = 0; d0 < 4; ++d0)
        Y[rowoff + d0 * 16 + lr] = f2bf(o[d0][r] * inv);
    }
  }
}

// ---------------- launch ----------------

extern "C" void kernel_launch(void* const* d_in, const int* in_sizes, int n_in,
                              void* d_out, int out_size, void* d_ws, size_t ws_size,
                              hipStream_t stream) {
  const float* x    = (const float*)d_in[0];
  const float* cosb = (const float*)d_in[1];
  const float* sinb = (const float*)d_in[2];
  const float* Wq   = (const float*)d_in[3];
  const float* Wk   = (const float*)d_in[4];
  const float* Wv   = (const float*)d_in[5];
  const float* Wo   = (const float*)d_in[6];
  float* out = (float*)d_out;

  // Buffer map:
  //   d_out (16 MB): QKVb [4096][1536] bf16 = 12 MB  (dead at final gemm)
  //   d_ws: xb 0..8M | Wqkvt 8..11M | Wot 11..13M ; Yb aliases xb after attn
  char* ob = (char*)d_out;
  char* ws = (char*)d_ws;
  const size_t MB = 1024 * 1024;
  unsigned short* QKVb  = (unsigned short*)(ob);
  unsigned short* xb    = (unsigned short*)(ws);
  unsigned short* Wqkvt = (unsigned short*)(ws + 8 * MB);
  unsigned short* Wot   = (unsigned short*)(ws + 11 * MB);
  unsigned short* Yb    = xb;   // x-content dead after QKV gemm

  conv_f32_to_bf16<<<4096, 256, 0, stream>>>(x, xb, 4096 * 1024);
  // pack W_qkv^T rows: [0,1024) = Wq, [1024,1280) = Wk, [1280,1536) = Wv
  transpose_conv<<<dim3(32, 32), dim3(32, 8), 0, stream>>>(Wq, Wqkvt, 1024, 1024);
  transpose_conv<<<dim3(8, 32), dim3(32, 8), 0, stream>>>(Wk, Wqkvt + (size_t)1024 * 1024, 1024, 256);
  transpose_conv<<<dim3(8, 32), dim3(32, 8), 0, stream>>>(Wv, Wqkvt + (size_t)1280 * 1024, 1024, 256);
  transpose_conv<<<dim3(32, 32), dim3(32, 8), 0, stream>>>(Wo, Wot, 1024, 1024);

  // fused QKV projection: [4096][1536] bf16
  gemm_bt<<<dim3(24, 32), 256, 0, stream>>>(xb, Wqkvt, QKVb, 4096, 1536, 1024, 0);

  // RoPE on Q (x0.125) + K in one pass
  rope_qk<<<10240, 256, 0, stream>>>(QKVb, cosb, sinb);

  // attention -> Yb bf16 [B*T][1024]
  attn_fused<<<dim3(512), 256, 0, stream>>>(QKVb, Yb);

  // output projection (fp32, overwrites d_out)
  gemm_bt<<<dim3(16, 32), 256, 0, stream>>>(Yb, Wot, out, 4096, 1024, 1024, 1);
}